// Round 4
// baseline (171.922 us; speedup 1.0000x reference)
//
#include <hip/hip_runtime.h>
#include <math.h>

#define EPS 1e-6f
#define IBLK 6
#define CHUNK 64
#define RSTRIDE 86   // 64 rows x (42 pred | 42 gt | 2 pad); even => b64-merge, 2-way bank alias (free)

typedef float v16f __attribute__((ext_vector_type(16)));
struct Row { v16f a, b, c; };   // 42 used of 48; constant-index access only => VGPR-resident

template<int K>
__device__ __forceinline__ void rset(Row& r, float v) {
    if constexpr (K < 16) r.a[K] = v;
    else if constexpr (K < 32) r.b[K - 16] = v;
    else r.c[K - 32] = v;
}
template<int K>
__device__ __forceinline__ float rget(const Row& r) {
    if constexpr (K < 16) return r.a[K];
    else if constexpr (K < 32) return r.b[K - 16];
    else return r.c[K - 32];
}
template<int K>
__device__ __forceinline__ void load_rows(const float* __restrict__ sm, int base, Row& x, Row& y) {
    if constexpr (K < 42) {
        rset<K>(x, sm[base + K]);
        rset<K>(y, sm[base + 42 + K]);
        load_rows<K + 1>(sm, base, x, y);
    }
}

struct MC { float m00,m01,m02,m10,m11,m12,m20,m21,m22,c0,c1,c2; };

template<int AT>
__device__ __forceinline__ void atom_accum(const Row& x, const Row& y, const MC& m,
                                           int mj, float& num) {
    if constexpr (AT < 14) {
        constexpr int k = AT * 3;
        float Y0 = rget<k>(y), Y1 = rget<k+1>(y), Y2 = rget<k+2>(y);
        float d0 = rget<k>(x)   - (m.m00*Y0 + m.m01*Y1 + m.m02*Y2 + m.c0);
        float d1 = rget<k+1>(x) - (m.m10*Y0 + m.m11*Y1 + m.m12*Y2 + m.c1);
        float d2 = rget<k+2>(x) - (m.m20*Y0 + m.m21*Y1 + m.m22*Y2 + m.c2);
        float s = d0*d0 + d1*d1 + d2*d2;
        float w = (float)((mj >> AT) & 1);
        num += w * sqrtf(fmaxf(s, EPS));
        atom_accum<AT + 1>(x, y, m, mj, num);
    }
}

struct F3 { float x, y, z; };
__device__ inline F3 sub3(F3 a, F3 b){return {a.x-b.x,a.y-b.y,a.z-b.z};}
__device__ inline float dot3(F3 a, F3 b){return a.x*b.x+a.y*b.y+a.z*b.z;}
__device__ inline F3 scale3(F3 a,float s){return {a.x*s,a.y*s,a.z*s};}
__device__ inline F3 cross3(F3 a,F3 b){return {a.y*b.z-a.z*b.y, a.z*b.x-a.x*b.z, a.x*b.y-a.y*b.x};}
__device__ inline F3 norm3(F3 v){float s=dot3(v,v);float inv=1.f/sqrtf(fmaxf(s,EPS));return scale3(v,inv);}

__device__ inline void make_frame(const float* __restrict__ base, float R[9], F3& ca) {
    F3 n = {base[0], base[1], base[2]};
    ca   = {base[3], base[4], base[5]};
    F3 c = {base[6], base[7], base[8]};
    F3 e1 = norm3(sub3(c, ca));
    F3 v2 = sub3(n, ca);
    float d = dot3(e1, v2);
    F3 e2 = norm3({v2.x - d*e1.x, v2.y - d*e1.y, v2.z - d*e1.z});
    F3 e3 = cross3(e1, e2);
    R[0]=e1.x; R[1]=e1.y; R[2]=e1.z;
    R[3]=e2.x; R[4]=e2.y; R[5]=e2.z;
    R[6]=e3.x; R[7]=e3.y; R[8]=e3.z;
}

// ---------------- prep: frames -> fused M,c per (l,i); packed; CA arrays; zero accums ----
__global__ __launch_bounds__(256) void prep_kernel(
    const float* __restrict__ pred, const float* __restrict__ gt,
    const float* __restrict__ atom_mask, const int* __restrict__ batch,
    const int* __restrict__ chain,
    float* __restrict__ Mc, int* __restrict__ packed,
    float* __restrict__ gtca, float* __restrict__ predca,
    float* __restrict__ lddt_s, float* __restrict__ lddt_c,
    float* __restrict__ acc, unsigned int* __restrict__ counter,
    int L, int N, int A)
{
    int idx = blockIdx.x * blockDim.x + threadIdx.x;
    if (idx == 0) { for (int k = 0; k < 8; k++) acc[k] = 0.f; *counter = 0u; }
    if (idx >= L * N) return;
    int l = idx / N, i = idx - l * N;

    float Rg[9]; F3 cag;
    make_frame(gt + (size_t)i * A * 3, Rg, cag);
    float Rp[9]; F3 cap;
    make_frame(pred + ((size_t)l * N + i) * A * 3, Rp, cap);

    float m[9];
    #pragma unroll
    for (int d = 0; d < 3; d++)
        #pragma unroll
        for (int e = 0; e < 3; e++)
            m[d*3+e] = Rp[0*3+d]*Rg[0*3+e] + Rp[1*3+d]*Rg[1*3+e] + Rp[2*3+d]*Rg[2*3+e];
    float c0 = cap.x - (m[0]*cag.x + m[1]*cag.y + m[2]*cag.z);
    float c1 = cap.y - (m[3]*cag.x + m[4]*cag.y + m[5]*cag.z);
    float c2 = cap.z - (m[6]*cag.x + m[7]*cag.y + m[8]*cag.z);

    float* o = Mc + (size_t)idx * 12;
    #pragma unroll
    for (int k = 0; k < 9; k++) o[k] = m[k];
    o[9] = c0; o[10] = c1; o[11] = c2;

    if (l == 0) {
        unsigned mm = 0;
        for (int a = 0; a < A; a++)
            if (atom_mask[(size_t)i * A + a] > 0.f) mm |= (1u << a);
        packed[i] = (int)(mm | ((unsigned)batch[i] << 16) | ((unsigned)chain[i] << 24));
        gtca[i*3] = cag.x; gtca[i*3+1] = cag.y; gtca[i*3+2] = cag.z;
        lddt_s[i] = 0.f; lddt_c[i] = 0.f;
    }
    if (l == L - 1) { predca[i*3] = cap.x; predca[i*3+1] = cap.y; predca[i*3+2] = cap.z; }
}

// ---------------- mega: thread owns j (row in VGPRs), block loops i; fused lddt + finalize ----
__global__ __launch_bounds__(256, 3) void fape_mega(
    const float* __restrict__ pred, const float* __restrict__ gt,
    const float* __restrict__ Mc, const int* __restrict__ packed,
    const float* __restrict__ gtca, const float* __restrict__ predca,
    float* __restrict__ acc,
    float* __restrict__ lddt_s, float* __restrict__ lddt_c,
    unsigned int* __restrict__ counter,
    float* __restrict__ out, float* __restrict__ out_final,
    float* __restrict__ out_rot, float* __restrict__ out_lddt,
    int L, int N, int gridTotal)
{
    __shared__ float smem[CHUNK * RSTRIDE];
    __shared__ float red[4][5];
    __shared__ float redf[4];
    __shared__ int flag;

    int t  = threadIdx.x;
    int it = blockIdx.x, jt = blockIdx.y, l = blockIdx.z;
    int j  = jt * 256 + t;
    int i0 = it * IBLK;
    bool last = (l == L - 1);

    int pkj = packed[j];
    int mjs = pkj & 0xFFFF;
    int bj  = (pkj >> 16) & 0xFF;
    int cjc = (pkj >> 24) & 0xFF;

    // ---- Phase B: coalesced global -> LDS bounce -> per-thread VGPR rows ----
    Row x{}, y{};
    const float* psrc = pred + ((size_t)l * N + (size_t)jt * 256) * 42;
    const float* gsrc = gt + ((size_t)jt * 256) * 42;
    for (int c = 0; c < 4; c++) {
        __syncthreads();
        for (int w = t; w < CHUNK * 42; w += 256) {
            int r = w / 42, cc = w - r * 42;
            smem[r * RSTRIDE + cc]      = psrc[(size_t)c * CHUNK * 42 + w];
            smem[r * RSTRIDE + 42 + cc] = gsrc[(size_t)c * CHUNK * 42 + w];
        }
        __syncthreads();
        if ((t >> 6) == c) {
            int base = (t & 63) * RSTRIDE;
            load_rows<0>(smem, base, x, y);
        }
    }

    // ---- Phase C: loop over i (uniform per block) ----
    float s_same = 0.f, s_other = 0.f, c_same = 0.f, c_other = 0.f, rot = 0.f;
    for (int ii = 0; ii < IBLK; ii++) {
        int i = i0 + ii;
        int pki = packed[i];   // uniform -> scalar load
        const float4* mcp = (const float4*)(Mc + ((size_t)l * N + i) * 12);
        float4 q0 = mcp[0], q1 = mcp[1], q2 = mcp[2];
        MC m = {q0.x, q0.y, q0.z, q0.w, q1.x, q1.y, q1.z, q1.w, q2.x, q2.y, q2.z, q2.w};
        int mi = pki & 0xFFFF;
        int bi = (pki >> 16) & 0xFF, ci = (pki >> 24) & 0xFF;

        int mj = mi & mjs;
        bool pm2 = (bj == bi) && (mj != 0);
        float fv = 0.f;
        if (__any(pm2)) {
            float num = 0.f;
            atom_accum<0>(x, y, m, mj, num);
            fv = pm2 ? num / (float)__popc((unsigned)mj) : 0.f;
        }
        if (last) out_final[(size_t)i * N + j] = fv;   // coalesced
        if (j == i) {
            rot += fv;
            if (last) out_rot[i] = fv;
        }
        if (pm2) {
            float cl = fminf(fv, 10.f);
            if (ci == cjc) { s_same += cl;  c_same += 1.f; }
            else           { s_other += cl; c_other += 1.f; }
        }
        if (last) {
            bool ok = (mi != 0) && (mjs != 0) && (j != i);
            if (__any(ok)) {
                float ls = 0.f, lc = 0.f;
                float dx = gtca[i*3]   - rget<3>(y);
                float dy = gtca[i*3+1] - rget<4>(y);
                float dz = gtca[i*3+2] - rget<5>(y);
                float gd = sqrtf(fmaxf(dx*dx + dy*dy + dz*dz, EPS));
                if (ok && gd < 15.f) {
                    float ex = predca[i*3]   - rget<3>(x);
                    float ey = predca[i*3+1] - rget<4>(x);
                    float ez = predca[i*3+2] - rget<5>(x);
                    float pd = sqrtf(fmaxf(ex*ex + ey*ey + ez*ez, EPS));
                    float de = fabsf(gd - pd);
                    ls = ((de < 0.5f ? 1.f : 0.f) + (de < 1.f ? 1.f : 0.f) +
                          (de < 2.f ? 1.f : 0.f) + (de < 4.f ? 1.f : 0.f)) * 0.25f;
                    lc = 1.f;
                }
                for (int o = 32; o > 0; o >>= 1) {
                    ls += __shfl_down(ls, o, 64);
                    lc += __shfl_down(lc, o, 64);
                }
                if ((t & 63) == 0) {
                    atomicAdd(&lddt_s[i], ls);
                    atomicAdd(&lddt_c[i], lc);
                }
            }
        }
    }

    // ---- block reduce 5 accumulators -> global atomics ----
    for (int o = 32; o > 0; o >>= 1) {
        s_same  += __shfl_down(s_same, o, 64);
        s_other += __shfl_down(s_other, o, 64);
        c_same  += __shfl_down(c_same, o, 64);
        c_other += __shfl_down(c_other, o, 64);
        rot     += __shfl_down(rot, o, 64);
    }
    int wave = t >> 6, lane = t & 63;
    if (lane == 0) {
        red[wave][0] = s_same; red[wave][1] = s_other;
        red[wave][2] = c_same; red[wave][3] = c_other; red[wave][4] = rot;
    }
    __syncthreads();
    if (t == 0) {
        float ss = 0, so = 0, cs = 0, co = 0, rt = 0;
        for (int w = 0; w < 4; w++) {
            ss += red[w][0]; so += red[w][1]; cs += red[w][2];
            co += red[w][3]; rt += red[w][4];
        }
        atomicAdd(&acc[l], ss);
        atomicAdd(&acc[L + l], so);
        if (l == 0) {
            atomicAdd(&acc[2 * L], cs);
            atomicAdd(&acc[2 * L + 1], co);
        }
        atomicAdd(&acc[2 * L + 2 + l], rt);
    }

    // ---- ticket: last block to finish does the finalize ----
    __threadfence();
    if (t == 0) {
        unsigned tk = atomicAdd(counter, 1u);
        flag = (tk == (unsigned)(gridTotal - 1)) ? 1 : 0;
    }
    __syncthreads();
    if (flag) {
        __threadfence();
        for (int i2 = t; i2 < N; i2 += 256)
            out_lddt[i2] = lddt_s[i2] / fmaxf(lddt_c[i2], 1e-6f);
        float nr = 0.f;
        for (int i2 = t; i2 < N; i2 += 256)
            nr += ((packed[i2] & 0xFFFF) != 0) ? 1.f : 0.f;
        for (int o = 32; o > 0; o >>= 1) nr += __shfl_down(nr, o, 64);
        __syncthreads();
        if (lane == 0) redf[wave] = nr;
        __syncthreads();
        if (t == 0) {
            float n_res = redf[0] + redf[1] + redf[2] + redf[3];
            float cs = fmaxf(acc[2 * L], 1e-6f);
            float co = fmaxf(acc[2 * L + 1], 1e-6f);
            float nrm = fmaxf(n_res, 1e-6f);
            for (int l2 = 0; l2 < L; l2++) {
                out[l2]     = acc[l2] / cs / 10.f + acc[L + l2] / co / 10.f;
                out[L + l2] = acc[2 * L + 2 + l2] / nrm;
            }
        }
    }
}

extern "C" void kernel_launch(void* const* d_in, const int* in_sizes, int n_in,
                              void* d_out, int out_size, void* d_ws, size_t ws_size,
                              hipStream_t stream)
{
    const float* pred      = (const float*)d_in[0];
    const float* gt        = (const float*)d_in[1];
    const float* atom_mask = (const float*)d_in[2];
    const int*   batch     = (const int*)d_in[3];
    const int*   chain     = (const int*)d_in[4];

    int N = in_sizes[3];
    int A = in_sizes[2] / N;
    int L = in_sizes[0] / (N * A * 3);

    float* out = (float*)d_out;
    float* out_final = out + 2 * L;
    float* out_rot   = out_final + (size_t)N * N;
    float* out_lddt  = out_rot + N;

    float* ws = (float*)d_ws;
    float* Mc      = ws;                                  // L*N*12
    float* gtca    = Mc + (size_t)L * N * 12;             // N*3
    float* predca  = gtca + (size_t)N * 3;                // N*3
    float* lddt_s  = predca + (size_t)N * 3;              // N
    float* lddt_c  = lddt_s + N;                          // N
    float* acc     = lddt_c + N;                          // 8
    unsigned int* counter = (unsigned int*)(acc + 8);     // 1
    int* packed    = (int*)(counter + 1);                 // N

    int totalP = L * N;
    prep_kernel<<<(totalP + 255) / 256, 256, 0, stream>>>(
        pred, gt, atom_mask, batch, chain,
        Mc, packed, gtca, predca, lddt_s, lddt_c, acc, counter, L, N, A);

    int IT = N / IBLK;        // 128
    int JT = N / 256;         // 3
    dim3 grid(IT, JT, L);     // 768 blocks
    int gridTotal = IT * JT * L;
    fape_mega<<<grid, 256, 0, stream>>>(
        pred, gt, Mc, packed, gtca, predca,
        acc, lddt_s, lddt_c, counter,
        out, out_final, out_rot, out_lddt, L, N, gridTotal);
}

// Round 5
// 153.417 us; speedup vs baseline: 1.1206x; 1.1206x over previous
//
#include <hip/hip_runtime.h>
#include <math.h>

#define EPS 1e-6f
#define JTILE 64     // j rows per block (one per lane)
#define IPW 6        // i per wave
#define NWAVE 4
#define ITILE (IPW * NWAVE)   // 24 i per block

struct F3 { float x, y, z; };
__device__ inline F3 sub3(F3 a, F3 b){return {a.x-b.x,a.y-b.y,a.z-b.z};}
__device__ inline float dot3(F3 a, F3 b){return a.x*b.x+a.y*b.y+a.z*b.z;}
__device__ inline F3 scale3(F3 a,float s){return {a.x*s,a.y*s,a.z*s};}
__device__ inline F3 cross3(F3 a,F3 b){return {a.y*b.z-a.z*b.y, a.z*b.x-a.x*b.z, a.x*b.y-a.y*b.x};}
__device__ inline F3 norm3(F3 v){float s=dot3(v,v);float inv=1.f/sqrtf(fmaxf(s,EPS));return scale3(v,inv);}

__device__ inline void make_frame(const float* __restrict__ base, float R[9], F3& ca) {
    F3 n = {base[0], base[1], base[2]};
    ca   = {base[3], base[4], base[5]};
    F3 c = {base[6], base[7], base[8]};
    F3 e1 = norm3(sub3(c, ca));
    F3 v2 = sub3(n, ca);
    float d = dot3(e1, v2);
    F3 e2 = norm3({v2.x - d*e1.x, v2.y - d*e1.y, v2.z - d*e1.z});
    F3 e3 = cross3(e1, e2);
    R[0]=e1.x; R[1]=e1.y; R[2]=e1.z;
    R[3]=e2.x; R[4]=e2.y; R[5]=e2.z;
    R[6]=e3.x; R[7]=e3.y; R[8]=e3.z;
}

// ---------------- prep: frames -> fused M,c per (l,i); packed; CA arrays; zero accums ----
__global__ __launch_bounds__(256) void prep_kernel(
    const float* __restrict__ pred, const float* __restrict__ gt,
    const float* __restrict__ atom_mask, const int* __restrict__ batch,
    const int* __restrict__ chain,
    float* __restrict__ Mc, int* __restrict__ packed,
    float* __restrict__ gtca, float* __restrict__ predca,
    float* __restrict__ lddt_s, float* __restrict__ lddt_c,
    float* __restrict__ acc, unsigned int* __restrict__ counter,
    int L, int N, int A)
{
    int idx = blockIdx.x * blockDim.x + threadIdx.x;
    if (idx == 0) { for (int k = 0; k < 8; k++) acc[k] = 0.f; *counter = 0u; }
    if (idx >= L * N) return;
    int l = idx / N, i = idx - l * N;

    float Rg[9]; F3 cag;
    make_frame(gt + (size_t)i * A * 3, Rg, cag);
    float Rp[9]; F3 cap;
    make_frame(pred + ((size_t)l * N + i) * A * 3, Rp, cap);

    float m[9];
    #pragma unroll
    for (int d = 0; d < 3; d++)
        #pragma unroll
        for (int e = 0; e < 3; e++)
            m[d*3+e] = Rp[0*3+d]*Rg[0*3+e] + Rp[1*3+d]*Rg[1*3+e] + Rp[2*3+d]*Rg[2*3+e];
    float c0 = cap.x - (m[0]*cag.x + m[1]*cag.y + m[2]*cag.z);
    float c1 = cap.y - (m[3]*cag.x + m[4]*cag.y + m[5]*cag.z);
    float c2 = cap.z - (m[6]*cag.x + m[7]*cag.y + m[8]*cag.z);

    float* o = Mc + (size_t)idx * 12;
    #pragma unroll
    for (int k = 0; k < 9; k++) o[k] = m[k];
    o[9] = c0; o[10] = c1; o[11] = c2;

    if (l == 0) {
        unsigned mm = 0;
        for (int a = 0; a < A; a++)
            if (atom_mask[(size_t)i * A + a] > 0.f) mm |= (1u << a);
        packed[i] = (int)(mm | ((unsigned)batch[i] << 16) | ((unsigned)chain[i] << 24));
        gtca[i*3] = cag.x; gtca[i*3+1] = cag.y; gtca[i*3+2] = cag.z;
        lddt_s[i] = 0.f; lddt_c[i] = 0.f;
    }
    if (l == L - 1) { predca[i*3] = cap.x; predca[i*3+1] = cap.y; predca[i*3+2] = cap.z; }
}

// ---------------- mega: lane owns j (row in LDS), wave loops i; fused lddt + finalize ----
// LDS row layout (per j, 84 floats = 21 float4, atom-interleaved):
//   atom a occupies floats [6a..6a+5] = x0 x1 x2 y0 y1 y2.
// Lane reads float4 index lane*21 + k : stride 21 is odd -> uniform over the 8
// float4-bank-groups -> conflict-free ds_read_b128.
__global__ __launch_bounds__(256) void fape_mega(
    const float* __restrict__ pred, const float* __restrict__ gt,
    const float* __restrict__ Mc, const int* __restrict__ packed,
    const float* __restrict__ gtca, const float* __restrict__ predca,
    float* __restrict__ acc,
    float* __restrict__ lddt_s, float* __restrict__ lddt_c,
    unsigned int* __restrict__ counter,
    float* __restrict__ out, float* __restrict__ out_final,
    float* __restrict__ out_rot, float* __restrict__ out_lddt,
    int L, int N, int gridTotal)
{
    __shared__ float smem[JTILE * 84];
    __shared__ float red[NWAVE][5];
    __shared__ float redf[NWAVE];
    __shared__ int flag;

    int t = threadIdx.x;
    int lane = t & 63, wave = t >> 6;
    int it = blockIdx.x, jt = blockIdx.y, l = blockIdx.z;
    int j0 = jt * JTILE;
    int j = j0 + lane;
    bool last = (l == L - 1);

    // ---- stage 64 rows, coalesced + conflict-free (linear f) ----
    const float* psrc = pred + ((size_t)l * N + j0) * 42;
    const float* gsrc = gt + (size_t)j0 * 42;
    for (int f = t; f < JTILE * 84; f += 256) {
        int r = f / 84, c = f - r * 84;
        int a = c / 6, p = c - a * 6;
        float v = (p < 3) ? psrc[r * 42 + a * 3 + p] : gsrc[r * 42 + a * 3 + p - 3];
        smem[f] = v;
    }
    __syncthreads();

    int pkj = packed[j];
    int mjs = pkj & 0xFFFF;
    int bj  = (pkj >> 16) & 0xFF;
    int cjc = (pkj >> 24) & 0xFF;

    const float4* rowp = (const float4*)(smem) + lane * 21;

    float s_same = 0.f, s_other = 0.f, c_same = 0.f, c_other = 0.f, rot = 0.f;

    for (int q = 0; q < IPW; q++) {
        int i = it * ITILE + wave * IPW + q;
        int pki = packed[i];   // wave-uniform -> scalar load
        const float4* mcp = (const float4*)(Mc + ((size_t)l * N + i) * 12);
        float4 q0 = mcp[0], q1 = mcp[1], q2 = mcp[2];
        float m00 = q0.x, m01 = q0.y, m02 = q0.z;
        float m10 = q0.w, m11 = q1.x, m12 = q1.y;
        float m20 = q1.z, m21 = q1.w, m22 = q2.x;
        float c0 = q2.y, c1 = q2.z, c2 = q2.w;
        int mi = pki & 0xFFFF;
        int bi = (pki >> 16) & 0xFF, ci = (pki >> 24) & 0xFF;

        int mj = mi & mjs;
        bool pm2 = (bj == bi) && (mj != 0);
        float fv = 0.f;
        if (__any(pm2)) {
            float num = 0.f;
            #pragma unroll
            for (int g = 0; g < 7; g++) {
                float4 va = rowp[g*3], vb = rowp[g*3+1], vc = rowp[g*3+2];
                // atom 2g: x = va.xyz, y = (va.w, vb.x, vb.y)
                {
                    float Y0 = va.w, Y1 = vb.x, Y2 = vb.y;
                    float d0 = va.x - (m00*Y0 + m01*Y1 + m02*Y2 + c0);
                    float d1 = va.y - (m10*Y0 + m11*Y1 + m12*Y2 + c1);
                    float d2 = va.z - (m20*Y0 + m21*Y1 + m22*Y2 + c2);
                    float w = (float)((mj >> (2*g)) & 1);
                    num += w * sqrtf(fmaxf(d0*d0 + d1*d1 + d2*d2, EPS));
                }
                // atom 2g+1: x = (vb.z, vb.w, vc.x), y = (vc.y, vc.z, vc.w)
                {
                    float Y0 = vc.y, Y1 = vc.z, Y2 = vc.w;
                    float d0 = vb.z - (m00*Y0 + m01*Y1 + m02*Y2 + c0);
                    float d1 = vb.w - (m10*Y0 + m11*Y1 + m12*Y2 + c1);
                    float d2 = vc.x - (m20*Y0 + m21*Y1 + m22*Y2 + c2);
                    float w = (float)((mj >> (2*g+1)) & 1);
                    num += w * sqrtf(fmaxf(d0*d0 + d1*d1 + d2*d2, EPS));
                }
            }
            fv = pm2 ? num / (float)__popc((unsigned)mj) : 0.f;
        }
        if (last) out_final[(size_t)i * N + j] = fv;   // 64 consecutive j: coalesced
        if (j == i) {
            rot += fv;
            if (last) out_rot[i] = fv;
        }
        if (pm2) {
            float cl = fminf(fv, 10.f);
            if (ci == cjc) { s_same += cl;  c_same += 1.f; }
            else           { s_other += cl; c_other += 1.f; }
        }
        if (last) {
            bool ok = (mi != 0) && (mjs != 0) && (j != i);
            if (__any(ok)) {
                float ls = 0.f, lc = 0.f;
                const float* row = smem + lane * 84;
                float dx = gtca[i*3]   - row[9];
                float dy = gtca[i*3+1] - row[10];
                float dz = gtca[i*3+2] - row[11];
                float gd = sqrtf(fmaxf(dx*dx + dy*dy + dz*dz, EPS));
                if (ok && gd < 15.f) {
                    float ex = predca[i*3]   - row[6];
                    float ey = predca[i*3+1] - row[7];
                    float ez = predca[i*3+2] - row[8];
                    float pd = sqrtf(fmaxf(ex*ex + ey*ey + ez*ez, EPS));
                    float de = fabsf(gd - pd);
                    ls = ((de < 0.5f ? 1.f : 0.f) + (de < 1.f ? 1.f : 0.f) +
                          (de < 2.f ? 1.f : 0.f) + (de < 4.f ? 1.f : 0.f)) * 0.25f;
                    lc = 1.f;
                }
                for (int o = 32; o > 0; o >>= 1) {
                    ls += __shfl_down(ls, o, 64);
                    lc += __shfl_down(lc, o, 64);
                }
                if (lane == 0) {
                    atomicAdd(&lddt_s[i], ls);
                    atomicAdd(&lddt_c[i], lc);
                }
            }
        }
    }

    // ---- block reduce 5 accumulators -> global atomics ----
    for (int o = 32; o > 0; o >>= 1) {
        s_same  += __shfl_down(s_same, o, 64);
        s_other += __shfl_down(s_other, o, 64);
        c_same  += __shfl_down(c_same, o, 64);
        c_other += __shfl_down(c_other, o, 64);
        rot     += __shfl_down(rot, o, 64);
    }
    if (lane == 0) {
        red[wave][0] = s_same; red[wave][1] = s_other;
        red[wave][2] = c_same; red[wave][3] = c_other; red[wave][4] = rot;
    }
    __syncthreads();
    if (t == 0) {
        float ss = 0, so = 0, cs = 0, co = 0, rt = 0;
        for (int w = 0; w < NWAVE; w++) {
            ss += red[w][0]; so += red[w][1]; cs += red[w][2];
            co += red[w][3]; rt += red[w][4];
        }
        atomicAdd(&acc[l], ss);
        atomicAdd(&acc[L + l], so);
        if (l == 0) {
            atomicAdd(&acc[2 * L], cs);
            atomicAdd(&acc[2 * L + 1], co);
        }
        atomicAdd(&acc[2 * L + 2 + l], rt);
    }

    // ---- ticket: last block to finish does the finalize ----
    __threadfence();
    if (t == 0) {
        unsigned tk = atomicAdd(counter, 1u);
        flag = (tk == (unsigned)(gridTotal - 1)) ? 1 : 0;
    }
    __syncthreads();
    if (flag) {
        __threadfence();
        for (int i2 = t; i2 < N; i2 += 256)
            out_lddt[i2] = lddt_s[i2] / fmaxf(lddt_c[i2], 1e-6f);
        float nr = 0.f;
        for (int i2 = t; i2 < N; i2 += 256)
            nr += ((packed[i2] & 0xFFFF) != 0) ? 1.f : 0.f;
        for (int o = 32; o > 0; o >>= 1) nr += __shfl_down(nr, o, 64);
        __syncthreads();
        if (lane == 0) redf[wave] = nr;
        __syncthreads();
        if (t == 0) {
            float n_res = 0.f;
            for (int w = 0; w < NWAVE; w++) n_res += redf[w];
            float cs = fmaxf(acc[2 * L], 1e-6f);
            float co = fmaxf(acc[2 * L + 1], 1e-6f);
            float nrm = fmaxf(n_res, 1e-6f);
            for (int l2 = 0; l2 < L; l2++) {
                out[l2]     = acc[l2] / cs / 10.f + acc[L + l2] / co / 10.f;
                out[L + l2] = acc[2 * L + 2 + l2] / nrm;
            }
        }
    }
}

extern "C" void kernel_launch(void* const* d_in, const int* in_sizes, int n_in,
                              void* d_out, int out_size, void* d_ws, size_t ws_size,
                              hipStream_t stream)
{
    const float* pred      = (const float*)d_in[0];
    const float* gt        = (const float*)d_in[1];
    const float* atom_mask = (const float*)d_in[2];
    const int*   batch     = (const int*)d_in[3];
    const int*   chain     = (const int*)d_in[4];

    int N = in_sizes[3];
    int A = in_sizes[2] / N;
    int L = in_sizes[0] / (N * A * 3);

    float* out = (float*)d_out;
    float* out_final = out + 2 * L;
    float* out_rot   = out_final + (size_t)N * N;
    float* out_lddt  = out_rot + N;

    float* ws = (float*)d_ws;
    float* Mc      = ws;                                  // L*N*12
    float* gtca    = Mc + (size_t)L * N * 12;             // N*3
    float* predca  = gtca + (size_t)N * 3;                // N*3
    float* lddt_s  = predca + (size_t)N * 3;              // N
    float* lddt_c  = lddt_s + N;                          // N
    float* acc     = lddt_c + N;                          // 8
    unsigned int* counter = (unsigned int*)(acc + 8);     // 1
    int* packed    = (int*)(counter + 1);                 // N

    int totalP = L * N;
    prep_kernel<<<(totalP + 255) / 256, 256, 0, stream>>>(
        pred, gt, atom_mask, batch, chain,
        Mc, packed, gtca, predca, lddt_s, lddt_c, acc, counter, L, N, A);

    int IT = N / ITILE;       // 32
    int JT = N / JTILE;       // 12
    dim3 grid(IT, JT, L);     // 768 blocks
    int gridTotal = IT * JT * L;
    fape_mega<<<grid, 256, 0, stream>>>(
        pred, gt, Mc, packed, gtca, predca,
        acc, lddt_s, lddt_c, counter,
        out, out_final, out_rot, out_lddt, L, N, gridTotal);
}